// Round 8
// baseline (906.421 us; speedup 1.0000x reference)
//
#include <hip/hip_runtime.h>
#include <stdint.h>

#define NB  2
#define NC  128
#define NT  32768
#define KFB 512
#define NUP 2048
#define CAP 14336

typedef unsigned int u32;
typedef unsigned short u16;
typedef short s16;
typedef float f32x4 __attribute__((ext_vector_type(4)));
typedef s16 short8 __attribute__((ext_vector_type(8)));
typedef u32 u32x4 __attribute__((ext_vector_type(4)));

__device__ __forceinline__ u32 f2key(float v){
  u32 u = __float_as_uint(v);
  return (u & 0x80000000u) ? ~u : (u | 0x80000000u);
}
__device__ __forceinline__ float key2f(u32 k){
  u32 u = (k & 0x80000000u) ? (k & 0x7FFFFFFFu) : ~k;
  return __uint_as_float(u);
}
__device__ __forceinline__ u16 bf16rn(float v){
  u32 u = __float_as_uint(v);
  return (u16)((u + 0x7FFFu + ((u>>16)&1u)) >> 16);
}
__device__ __forceinline__ u32 packhl(float v){
  u16 h = bf16rn(v);
  u16 lo = bf16rn(v - __uint_as_float(((u32)h)<<16));
  return ((u32)h<<16) | lo;
}
__device__ __forceinline__ void unpack8(const u32* p, short8& xh, short8& xl){
  u32x4 r0 = *(const u32x4*)p;
  u32x4 r1 = *(const u32x4*)(p + 4);
  union { u32 u[4]; short8 v; } H, L;
  H.u[0] = __builtin_amdgcn_perm(r0.y, r0.x, 0x07060302u);
  H.u[1] = __builtin_amdgcn_perm(r0.w, r0.z, 0x07060302u);
  H.u[2] = __builtin_amdgcn_perm(r1.y, r1.x, 0x07060302u);
  H.u[3] = __builtin_amdgcn_perm(r1.w, r1.z, 0x07060302u);
  L.u[0] = __builtin_amdgcn_perm(r0.y, r0.x, 0x05040100u);
  L.u[1] = __builtin_amdgcn_perm(r0.w, r0.z, 0x05040100u);
  L.u[2] = __builtin_amdgcn_perm(r1.y, r1.x, 0x05040100u);
  L.u[3] = __builtin_amdgcn_perm(r1.w, r1.z, 0x05040100u);
  xh = H.v; xl = L.v;
}

// LDS row stride (u32) for [T][ci] tiles: 132 ≡ 4 (mod 32) -> uniform banks
#define RS 132

// ============ K_prep: init + split weights to bf16 hi/lo in MFMA A-fragment order ============
__global__ __launch_bounds__(256) void k_prep(const float* __restrict__ encw,
    const float* __restrict__ decw, const float* __restrict__ upw,
    const float* __restrict__ fbw,
    u16* __restrict__ wdil, u16* __restrict__ wup, u16* __restrict__ wfb,
    u32* __restrict__ h1, u32* __restrict__ h2, int* __restrict__ counts){
  int g = blockIdx.x*256 + threadIdx.x;
  if (g < 2048) h1[g] = 0u;
  else if (g < 4096) h2[g-2048] = 0u;
  if (g < NB) counts[g] = 0;
  if (g < 49152){
    int l = g & 63, mt = (g>>6)&7, s = (g>>9)&7, layer = g>>12;
    const float* W = (layer < 6) ? (encw + (size_t)layer*NC*NC*2)
                                 : (decw + (size_t)(layer-6)*NC*NC*2);
    int co = mt*16 + (l & 15);
    int kb = s*32 + ((l>>4)<<3);
    union { u16 h[8]; u32x4 q; } H, L;
    #pragma unroll
    for (int j=0;j<8;++j){
      int k = kb + j;
      float v = W[((size_t)co*NC + (k&127))*2 + (k>>7)];
      u16 h = bf16rn(v);
      H.h[j] = h;
      L.h[j] = bf16rn(v - __uint_as_float(((u32)h)<<16));
    }
    int unit = g >> 6;
    *(u32x4*)(wdil + (size_t)unit*1024 + (l<<3)) = H.q;
    *(u32x4*)(wdil + (size_t)unit*1024 + 512 + (l<<3)) = L.q;
  } else if (g < 81920){
    int g2 = g - 49152;
    int l = g2 & 63, umt = (g2>>6)&127, s = g2>>13;
    int u = umt*16 + (l & 15);
    int kb = s*32 + ((l>>4)<<3);
    union { u16 h[8]; u32x4 q; } H, L;
    #pragma unroll
    for (int j=0;j<8;++j){
      float v = upw[(size_t)u*NC + kb + j];
      u16 h = bf16rn(v);
      H.h[j] = h;
      L.h[j] = bf16rn(v - __uint_as_float(((u32)h)<<16));
    }
    int unit = g2 >> 6;
    *(u32x4*)(wup + (size_t)unit*1024 + (l<<3)) = H.q;
    *(u32x4*)(wup + (size_t)unit*1024 + 512 + (l<<3)) = L.q;
  } else if (g < 90112){
    int g3 = g - 81920;
    int l = g3 & 63, mt = (g3>>6)&7, s = g3>>9;
    int c = mt*16 + (l & 15);
    int kb = s*32 + ((l>>4)<<3);
    union { u16 h[8]; u32x4 q; } H, L;
    #pragma unroll
    for (int j=0;j<8;++j){
      float v = fbw[(size_t)c*KFB + kb + j];
      u16 h = bf16rn(v);
      H.h[j] = h;
      L.h[j] = bf16rn(v - __uint_as_float(((u32)h)<<16));
    }
    int unit = g3 >> 6;
    *(u32x4*)(wfb + (size_t)unit*1024 + (l<<3)) = H.q;
    *(u32x4*)(wfb + (size_t)unit*1024 + 512 + (l<<3)) = L.q;
  }
}

// ============ K1: filterbank analysis — bf16x3 MFMA ============
__global__ __launch_bounds__(256) void k_fb(const float* __restrict__ x,
    const u16* __restrict__ wfb, float* __restrict__ spec){
  __shared__ u32 xw[640];
  const int tid = threadIdx.x;
  const int t0 = blockIdx.x << 7;
  const int b  = blockIdx.y;
  const int lane = tid & 63, w = tid >> 6;
  const int wy = w >> 1, wx = w & 1;
  const int quad = lane >> 4, l15 = lane & 15;
  for (int i = tid; i < 640; i += 256){
    int t = t0 - 256 + i;
    float v = ((u32)t < (u32)NT) ? x[b*NT + t] : 0.0f;
    xw[i] = packhl(v);
  }
  __syncthreads();
  f32x4 acc[4][4] = {};
  for (int s = 0; s < 16; ++s){
    short8 ah[4], al[4];
    #pragma unroll
    for (int mt=0; mt<4; ++mt){
      const u16* p = wfb + (size_t)(s*8 + wy*4 + mt)*1024 + (lane<<3);
      ah[mt] = *(const short8*)p;
      al[mt] = *(const short8*)(p + 512);
    }
    short8 xh[4], xl[4];
    #pragma unroll
    for (int nt=0; nt<4; ++nt){
      int base = s*32 + quad*8 + (wx<<6) + (nt<<4) + l15;
      u32 r[8];
      #pragma unroll
      for (int j=0;j<8;++j) r[j] = xw[base + j];
      union { u32 u[4]; short8 v; } H, L;
      H.u[0] = __builtin_amdgcn_perm(r[1], r[0], 0x07060302u);
      H.u[1] = __builtin_amdgcn_perm(r[3], r[2], 0x07060302u);
      H.u[2] = __builtin_amdgcn_perm(r[5], r[4], 0x07060302u);
      H.u[3] = __builtin_amdgcn_perm(r[7], r[6], 0x07060302u);
      L.u[0] = __builtin_amdgcn_perm(r[1], r[0], 0x05040100u);
      L.u[1] = __builtin_amdgcn_perm(r[3], r[2], 0x05040100u);
      L.u[2] = __builtin_amdgcn_perm(r[5], r[4], 0x05040100u);
      L.u[3] = __builtin_amdgcn_perm(r[7], r[6], 0x05040100u);
      xh[nt] = H.v; xl[nt] = L.v;
    }
    #pragma unroll
    for (int mt=0; mt<4; ++mt){
      #pragma unroll
      for (int nt=0; nt<4; ++nt){
        acc[mt][nt] = __builtin_amdgcn_mfma_f32_16x16x32_bf16(ah[mt], xh[nt], acc[mt][nt], 0,0,0);
        acc[mt][nt] = __builtin_amdgcn_mfma_f32_16x16x32_bf16(ah[mt], xl[nt], acc[mt][nt], 0,0,0);
        acc[mt][nt] = __builtin_amdgcn_mfma_f32_16x16x32_bf16(al[mt], xh[nt], acc[mt][nt], 0,0,0);
      }
    }
  }
  #pragma unroll
  for (int mt=0; mt<4; ++mt){
    #pragma unroll
    for (int r=0; r<4; ++r){
      const int c = (wy<<6) + (mt<<4) + (quad<<2) + r;
      float* po = spec + (size_t)(b*NC+c)*NT + t0 + (wx<<6) + l15;
      #pragma unroll
      for (int nt=0; nt<4; ++nt) po[nt<<4] = acc[mt][nt][r];
    }
  }
}

// ============ K2: fused 6-layer dilated stack — packed u32 LDS (r6 core) + prefetch ============
// 1024 threads = 16 waves: wm 0..3 (32 co), wn 0..3 (64 t). LDS 256 x RS u32 = 135168 B.
__global__ __launch_bounds__(1024,4) void k_stack(const float* __restrict__ xin,
    float* __restrict__ xout, const u16* __restrict__ wf,
    const float* __restrict__ biases, int mode){
  extern __shared__ u32 lx[];           // [row 256][RS]
  const int tid = threadIdx.x;
  const int b  = blockIdx.y;
  const int T0 = blockIdx.x << 7;
  const int row0g = mode ? (T0 - 122) : T0;
  const int lane = tid & 63, w = tid >> 6;
  const int wm = w >> 2, wn = w & 3;
  const int quad = lane >> 4, l15 = lane & 15;
  // ---- stage-in: row = tid&255, 32 ci per thread, packed b128 writes
  {
    const float* xb = xin + (size_t)b*NC*NT;
    const int row = tid & 255;
    const int ci0 = (tid >> 8) << 5;
    const int tg = row0g + row;
    const bool ok = ((u32)tg < (u32)NT);
    const float* src = xb + (size_t)ci0*NT + tg;
    u32* dst = lx + row*RS + ci0;
    #pragma unroll
    for (int g=0; g<8; ++g){
      u32x4 q;
      #pragma unroll
      for (int k=0;k<4;++k){
        float v = ok ? src[(size_t)(g*4 + k)*NT] : 0.0f;
        q[k] = packhl(v);
      }
      *(u32x4*)(dst + g*4) = q;
    }
  }
  const int dils[6] = {1,3,9,27,81,1};
  const int Hrem[6] = {121,118,109,82,1,0};
  #pragma unroll 1
  for (int l = 0; l < 6; ++l){
    const int d = dils[l];
    const int o0 = mode ? -d : 0;
    const int o1 = mode ? 0 : d;
    const int lo = mode ? (122 - Hrem[l]) : 0;
    const int hi = mode ? 250 : (128 + Hrem[l]);
    const u16* wl = wf + ((size_t)l << 16);
    __syncthreads();
    bool act[4];
    #pragma unroll
    for (int nt=0;nt<4;++nt){
      const int Tst = (wn<<6) + (nt<<4);
      act[nt] = (Tst + 16 > lo) && (Tst < hi);
    }
    f32x4 acc[2][4] = {};
    short8 cah[2], cal[2], nah[2], nal[2];
    {
      const u16* p0 = wl + (size_t)(((wm<<1) + 0) << 10) + (lane<<3);
      const u16* p1 = wl + (size_t)(((wm<<1) + 1) << 10) + (lane<<3);
      cah[0] = *(const short8*)p0; cal[0] = *(const short8*)(p0 + 512);
      cah[1] = *(const short8*)p1; cal[1] = *(const short8*)(p1 + 512);
    }
    #pragma unroll 1
    for (int s = 0; s < 8; ++s){
      const int sn = (s < 7) ? (s + 1) : 7;
      const u16* p0 = wl + (size_t)(((sn<<3) + (wm<<1) + 0) << 10) + (lane<<3);
      const u16* p1 = wl + (size_t)(((sn<<3) + (wm<<1) + 1) << 10) + (lane<<3);
      nah[0] = *(const short8*)p0; nal[0] = *(const short8*)(p0 + 512);
      nah[1] = *(const short8*)p1; nal[1] = *(const short8*)(p1 + 512);
      const int o = (s >= 4) ? o1 : o0;
      const int cig = (s & 3) << 5;
      #pragma unroll
      for (int nt=0;nt<4;++nt){
        if (!act[nt]) continue;
        const int T = ((wn<<6) + (nt<<4) + l15 + o) & 255;
        const int idx = T*RS + cig + (quad<<3);
        short8 xh, xl;
        unpack8(&lx[idx], xh, xl);
        acc[0][nt] = __builtin_amdgcn_mfma_f32_16x16x32_bf16(cah[0], xh, acc[0][nt], 0,0,0);
        acc[0][nt] = __builtin_amdgcn_mfma_f32_16x16x32_bf16(cah[0], xl, acc[0][nt], 0,0,0);
        acc[0][nt] = __builtin_amdgcn_mfma_f32_16x16x32_bf16(cal[0], xh, acc[0][nt], 0,0,0);
        acc[1][nt] = __builtin_amdgcn_mfma_f32_16x16x32_bf16(cah[1], xh, acc[1][nt], 0,0,0);
        acc[1][nt] = __builtin_amdgcn_mfma_f32_16x16x32_bf16(cah[1], xl, acc[1][nt], 0,0,0);
        acc[1][nt] = __builtin_amdgcn_mfma_f32_16x16x32_bf16(cal[1], xh, acc[1][nt], 0,0,0);
      }
      cah[0] = nah[0]; cal[0] = nal[0];
      cah[1] = nah[1]; cal[1] = nal[1];
    }
    __syncthreads();
    // ---- epilogue
    const float* bl = biases + l*NC;
    const bool last = (l == 5);
    #pragma unroll
    for (int mt=0;mt<2;++mt){
      const int cobase = (wm<<5) + (mt<<4) + (quad<<2);
      float bv[4];
      #pragma unroll
      for (int r=0;r<4;++r) bv[r] = bl[cobase + r];
      #pragma unroll
      for (int nt=0;nt<4;++nt){
        if (!act[nt]) continue;
        const int T = (wn<<6) + (nt<<4) + l15;
        const int idx = T*RS + cobase;
        u32x4 xo = *(const u32x4*)&lx[idx];
        const int tg = row0g + T;
        const bool tvld = ((u32)tg < (u32)NT);
        float nv[4];
        #pragma unroll
        for (int r=0;r<4;++r){
          float oldv = __uint_as_float(xo[r] & 0xFFFF0000u) + __uint_as_float(xo[r] << 16);
          float h = acc[mt][nt][r] + bv[r];
          h = (h >= 0.f) ? h : 0.2f*h;
          float xn = oldv + h;
          nv[r] = tvld ? xn : 0.0f;
        }
        if (!last){
          u32x4 np;
          #pragma unroll
          for (int r=0;r<4;++r) np[r] = packhl(nv[r]);
          *(u32x4*)&lx[idx] = np;
        } else {
          const bool rowok = mode ? (T >= 122 && T < 250) : (T < 128);
          if (rowok){
            float* po = xout + (size_t)(b*NC + cobase)*NT + tg;
            #pragma unroll
            for (int r=0;r<4;++r) po[(size_t)r*NT] = nv[r];
          }
        }
      }
    }
  }
}

// ============ K3a: up-proj on t-subsample (fp32, keys + coarse hist) ============
__global__ __launch_bounds__(256) void k_sub(const float* __restrict__ enc,
                                             const float* __restrict__ upw,
                                             const float* __restrict__ upb,
                                             u32* __restrict__ keys,
                                             u32* __restrict__ hist1){
  const int u0 = blockIdx.x * 64;
  const int i0 = blockIdx.y * 256;
  const int b  = blockIdx.z;
  __shared__ float uwl[32][68];
  __shared__ float ec[32][260];
  __shared__ u32 lh[1024];
  const int tid = threadIdx.x;
  for (int i=tid;i<1024;i+=256) lh[i] = 0u;
  const int ug = tid & 15;
  const int ig = tid >> 4;
  float acc[4][16];
  #pragma unroll
  for (int i=0;i<4;++i){
    #pragma unroll
    for (int j=0;j<16;++j) acc[i][j]=0.0f;
  }
  for (int c0=0;c0<NC;c0+=32){
    __syncthreads();
    #pragma unroll
    for (int i=0;i<8;++i){
      int flat = i*256+tid;
      uwl[flat & 31][flat >> 5] = upw[(size_t)(u0 + (flat>>5))*NC + c0 + (flat&31)];
    }
    #pragma unroll
    for (int i=0;i<32;++i){
      int flat = i*256+tid;
      ec[flat >> 8][flat & 255] = enc[(size_t)(b*NC + c0 + (flat>>8))*NT + (size_t)(i0 + (flat&255))*32];
    }
    __syncthreads();
    #pragma unroll 2
    for (int cc=0;cc<32;++cc){
      float a[4], bb[16];
      *(float4*)&a[0] = *(const float4*)&uwl[cc][ug*4];
      #pragma unroll
      for (int m=0;m<4;++m)
        *(float4*)&bb[m*4] = *(const float4*)&ec[cc][ig*16 + m*4];
      #pragma unroll
      for (int i=0;i<4;++i){
        #pragma unroll
        for (int j=0;j<16;++j)
          acc[i][j] = fmaf(a[i], bb[j], acc[i][j]);
      }
    }
  }
  #pragma unroll
  for (int i=0;i<4;++i){
    int u = u0 + ug*4 + i;
    float ub = upb[u];
    #pragma unroll
    for (int j=0;j<16;++j){
      float v = acc[i][j] + ub;
      u32 k = f2key(v);
      keys[(size_t)(b*NUP + u)*1024 + i0 + ig*16 + j] = k;
      atomicAdd(&lh[k >> 22], 1u);
    }
  }
  __syncthreads();
  for (int i=tid;i<1024;i+=256){
    u32 c = lh[i];
    if (c) atomicAdd(&hist1[b*1024 + i], c);
  }
}

// ============ K3sel: suffix-scan histogram, pick rank-64 bin ============
__global__ __launch_bounds__(256) void k_sel(const u32* __restrict__ hist,
                                             u32* __restrict__ cstar,
                                             u32* __restrict__ nab,
                                             u32* __restrict__ t0key,
                                             int phase){
  const int b = blockIdx.x;
  __shared__ u32 s1[1024];
  __shared__ u32 s2[1024];
  __shared__ int red[256];
  const int tid = threadIdx.x;
  for (int i=tid;i<1024;i+=256) s1[i] = hist[b*1024 + i];
  __syncthreads();
  u32* cur = s1; u32* nxt = s2;
  for (int off=1; off<1024; off<<=1){
    for (int i=tid;i<1024;i+=256){
      u32 v = cur[i];
      if (i + off < 1024) v += cur[i+off];
      nxt[i] = v;
    }
    __syncthreads();
    u32* t = cur; cur = nxt; nxt = t;
  }
  u32 off0 = (phase==1) ? 0u : nab[b];
  int best = -1;
  for (int i=tid;i<1024;i+=256)
    if (off0 + cur[i] >= 64u && i > best) best = i;
  red[tid] = best;
  __syncthreads();
  for (int st=128; st>0; st>>=1){
    if (tid < st) red[tid] = max(red[tid], red[tid+st]);
    __syncthreads();
  }
  if (tid == 0){
    int bi = (red[0] < 0) ? 0 : red[0];
    if (phase == 1){
      cstar[b] = (u32)bi;
      nab[b] = (bi < 1023) ? cur[bi+1] : 0u;
    } else {
      t0key[b] = (cstar[b] << 22) | (((u32)bi) << 12);
    }
  }
}

// ============ K3h2: fine histogram within coarse bin ============
__global__ void k_h2(const u32* __restrict__ keys, const u32* __restrict__ cstar,
                     u32* __restrict__ hist2){
  const u32 c0 = cstar[0], c1 = cstar[1];
  int i = blockIdx.x*256 + threadIdx.x;
  const int total = NB*NUP*1024;
  const int stride = gridDim.x*256;
  for (; i < total; i += stride){
    u32 k = keys[i];
    u32 cs = (i >> 21) ? c1 : c0;
    if ((k >> 22) == cs) atomicAdd(&hist2[((u32)(i>>21)<<10) + ((k>>12) & 1023u)], 1u);
  }
}

// ============ K3b: full up-proj — split hi/lo LDS, flattened (uc,s) loop w/ prefetch ============
#define RSH 136
__global__ __launch_bounds__(256,2) void k_up(const float* __restrict__ enc,
    const u16* __restrict__ wf, const float* __restrict__ upb,
    const u32* __restrict__ t0key, float* __restrict__ cval,
    int* __restrict__ cidx, int* __restrict__ counts){
  extern __shared__ u16 ls[];
  u16* lhh = ls;
  u16* lll = ls + 128*RSH;
  const int tid = threadIdx.x;
  const int t0 = blockIdx.x << 7;
  const int b  = blockIdx.y;
  const int lane = tid & 63, w = tid >> 6;
  const int wy = w >> 1, wx = w & 1;
  const int quad = lane >> 4, l15 = lane & 15;
  {
    const float* xb = enc + (size_t)b*NC*NT + t0;
    const int row = tid >> 1;
    const int ci0 = (tid & 1) << 6;
    const float* src = xb + (size_t)ci0*NT + row;
    u16* dh = lhh + row*RSH + ci0;
    u16* dl = lll + row*RSH + ci0;
    #pragma unroll
    for (int g=0; g<8; ++g){
      union { u16 h[8]; short8 v; } H, L;
      #pragma unroll
      for (int j=0;j<8;++j){
        float v = src[(size_t)(g*8 + j)*NT];
        u16 hh = bf16rn(v);
        H.h[j] = hh;
        L.h[j] = bf16rn(v - __uint_as_float(((u32)hh)<<16));
      }
      *(short8*)(dh + (g<<3)) = H.v;
      *(short8*)(dl + (g<<3)) = L.v;
    }
  }
  __syncthreads();
  float T0 = key2f(t0key[b]);
  T0 -= fabsf(T0)*3e-4f + 1e-5f;
  short8 cah[4], cal[4], nah[4], nal[4];
  {
    #pragma unroll
    for (int mt=0;mt<4;++mt){
      const u16* p = wf + (size_t)((wy*4 + mt) << 10) + (lane<<3);
      cah[mt] = *(const short8*)p; cal[mt] = *(const short8*)(p + 512);
    }
  }
  f32x4 acc[4][4] = {};
  #pragma unroll 1
  for (int ss = 0; ss < 64; ++ss){
    const int uc = ss >> 2, s = ss & 3;
    const int ssn = (ss < 63) ? (ss + 1) : 63;
    const int ucn = ssn >> 2, sn = ssn & 3;
    #pragma unroll
    for (int mt=0;mt<4;++mt){
      const u16* p = wf + (size_t)((sn*128 + ucn*8 + wy*4 + mt) << 10) + (lane<<3);
      nah[mt] = *(const short8*)p; nal[mt] = *(const short8*)(p + 512);
    }
    const int cig = s << 5;
    #pragma unroll
    for (int nt=0;nt<4;++nt){
      const int T = (wx<<6) + (nt<<4) + l15;
      const int base = T*RSH + cig + (quad<<3);
      short8 xh = *(const short8*)&lhh[base];
      short8 xl = *(const short8*)&lll[base];
      #pragma unroll
      for (int mt=0;mt<4;++mt){
        acc[mt][nt] = __builtin_amdgcn_mfma_f32_16x16x32_bf16(cah[mt], xh, acc[mt][nt], 0,0,0);
        acc[mt][nt] = __builtin_amdgcn_mfma_f32_16x16x32_bf16(cah[mt], xl, acc[mt][nt], 0,0,0);
        acc[mt][nt] = __builtin_amdgcn_mfma_f32_16x16x32_bf16(cal[mt], xh, acc[mt][nt], 0,0,0);
      }
    }
    if (s == 3){
      #pragma unroll
      for (int mt=0; mt<4; ++mt){
        #pragma unroll
        for (int r=0; r<4; ++r){
          int u = uc*128 + (wy<<6) + (mt<<4) + (quad<<2) + r;
          float ub = upb[u];
          #pragma unroll
          for (int nt=0; nt<4; ++nt){
            float v = acc[mt][nt][r] + ub;
            if (v >= T0){
              int slot = atomicAdd(&counts[b], 1);
              if (slot < CAP){
                cval[b*CAP + slot] = v;
                cidx[b*CAP + slot] = u*NT + (t0 + (wx<<6) + (nt<<4) + l15);
              }
            }
          }
        }
      }
      #pragma unroll
      for (int mt=0;mt<4;++mt)
        #pragma unroll
        for (int nt=0;nt<4;++nt) acc[mt][nt] = (f32x4){0.f,0.f,0.f,0.f};
    }
    #pragma unroll
    for (int mt=0;mt<4;++mt){ cah[mt] = nah[mt]; cal[mt] = nal[mt]; }
  }
}

// ============ K3c: exact top-64 — register-cached path for n<=8192 ============
__global__ __launch_bounds__(256) void k_top(const float* __restrict__ cval,
                                             const int* __restrict__ cidx,
                                             const int* __restrict__ counts,
                                             float* __restrict__ tv,
                                             int* __restrict__ ti){
  const int b = blockIdx.x;
  __shared__ float lv[CAP];
  __shared__ float sv[256];
  __shared__ int   si[256];
  const int tid = threadIdx.x;
  int n = counts[b]; if (n > CAP) n = CAP;
  if (n <= 8192){
    float v[32];
    #pragma unroll
    for (int r=0;r<32;++r){
      int i = r*256 + tid;
      v[r] = (i < n) ? cval[b*CAP+i] : -3.4e38f;
    }
    const int lane = tid & 63, wv = tid >> 6;
    for (int r=0;r<64;++r){
      float best = v[0]; int bidx = 0;
      #pragma unroll
      for (int k=1;k<32;++k){ if (v[k] > best){ best = v[k]; bidx = k; } }
      int gi = bidx*256 + tid;
      #pragma unroll
      for (int off=32; off>0; off>>=1){
        float ov = __shfl_down(best, off);
        int oi = __shfl_down(gi, off);
        if (ov > best){ best = ov; gi = oi; }
      }
      if (lane == 0){ sv[wv] = best; si[wv] = gi; }
      __syncthreads();
      if (tid == 0){
        float bb = sv[0]; int bbi = si[0];
        #pragma unroll
        for (int k=1;k<4;++k) if (sv[k] > bb){ bb = sv[k]; bbi = si[k]; }
        si[4] = bbi;
        if (bb > -3.0e38f){ tv[b*64+r] = bb; ti[b*64+r] = cidx[b*CAP + bbi]; }
        else { tv[b*64+r] = 0.0f; ti[b*64+r] = 0; }
      }
      __syncthreads();
      int wini = si[4];
      if ((wini & 255) == tid) v[wini >> 8] = -3.4e38f;
    }
  } else {
    for (int i=tid;i<n;i+=256) lv[i] = cval[b*CAP+i];
    __syncthreads();
    for (int r=0;r<64;++r){
      float best = -3.4e38f; int bi = -1;
      for (int i=tid;i<n;i+=256){
        float v = lv[i];
        if (v > best){ best = v; bi = i; }
      }
      sv[tid]=best; si[tid]=bi;
      __syncthreads();
      for (int st=128; st>0; st>>=1){
        if (tid < st && sv[tid+st] > sv[tid]){ sv[tid]=sv[tid+st]; si[tid]=si[tid+st]; }
        __syncthreads();
      }
      if (tid == 0){
        int kb = si[0];
        if (kb >= 0){
          tv[b*64+r] = sv[0];
          ti[b*64+r] = cidx[b*CAP+kb];
          lv[kb] = -3.4e38f;
        } else { tv[b*64+r] = 0.0f; ti[b*64+r] = 0; }
      }
      __syncthreads();
    }
  }
}

// ============ K4: fused decoder-input init: bias fill + spike scatter ============
__global__ void k_dec0(float* __restrict__ dst, const float* __restrict__ dnb,
                       const float* __restrict__ dnw,
                       const float* __restrict__ tv, const int* __restrict__ ti){
  const int b = blockIdx.x >> 7, c = blockIdx.x & 127;
  float v = dnb[c];
  float4 vv; vv.x=v; vv.y=v; vv.z=v; vv.w=v;
  float* row = dst + (size_t)(b*NC+c)*NT;
  for (int i=threadIdx.x; i < NT/4; i += 256) *(float4*)&row[i*4] = vv;
  __syncthreads();
  if (threadIdx.x < 64){
    int r = threadIdx.x;
    float sv = tv[b*64+r];
    int idx = ti[b*64+r];
    int u = idx / NT, t = idx - u*NT;
    atomicAdd(&row[t], dnw[(size_t)c*NUP + u] * sv);
  }
}

// ============ K6: transposed filterbank synthesis — TS 8192, 512 threads ============
#define TS 8192
#define WR 545   // col stride? rows 16 x cols 545; 545 % 32 == 1
__global__ __launch_bounds__(512) void k_syn(const float* __restrict__ dec,
                                             const float* __restrict__ fb,
                                             float* __restrict__ part){
  const int ts = blockIdx.x;    // 4
  const int c  = blockIdx.y;    // 128
  const int b  = blockIdx.z;
  const int t0 = ts * TS;
  __shared__ float win2[16*WR];
  __shared__ float fbl[512];
  const int tid = threadIdx.x;
  const int tl = tid * 16;
  float acc[16];
  #pragma unroll
  for (int j=0;j<16;++j) acc[j] = 0.0f;
  for (int i=tid; i < TS+511; i += 512){
    int t = t0 - 255 + i;
    win2[(i & 15)*WR + (i >> 4)] = ((u32)t < (u32)NT) ? dec[(size_t)(b*NC+c)*NT + t] : 0.0f;
  }
  if (tid < 512) fbl[tid] = fb[c*KFB + tid];
  __syncthreads();
  float w[23];
  #pragma unroll
  for (int k=0;k<23;++k){
    int i = tl + 504 + k;
    w[k] = win2[(i & 15)*WR + (i >> 4)];
  }
  for (int G=0; G<64; ++G){
    float4 f0 = *(const float4*)&fbl[G*8];
    float4 f1 = *(const float4*)&fbl[G*8+4];
    float fq[8] = {f0.x, f0.y, f0.z, f0.w, f1.x, f1.y, f1.z, f1.w};
    #pragma unroll
    for (int q=0;q<8;++q){
      #pragma unroll
      for (int jj=0;jj<16;++jj)
        acc[jj] = fmaf(fq[q], w[7-q+jj], acc[jj]);
    }
    if (G != 63){
      #pragma unroll
      for (int k=22;k>=8;--k) w[k] = w[k-8];
      #pragma unroll
      for (int k=0;k<8;++k){
        int i = tl + 496 - 8*G + k;
        w[k] = win2[(i & 15)*WR + (i >> 4)];
      }
    }
  }
  float* po = &part[(size_t)(c*NB + b)*NT + t0 + tl];
  #pragma unroll
  for (int m=0;m<4;++m){
    float4 ov; ov.x=acc[m*4+0]; ov.y=acc[m*4+1]; ov.z=acc[m*4+2]; ov.w=acc[m*4+3];
    *(float4*)&po[m*4] = ov;
  }
}

// ============ K6r: reduce 128 partial slices -> out (float4) ============
__global__ void k_red(const float* __restrict__ part, float* __restrict__ out){
  int i4 = blockIdx.x*256 + threadIdx.x;   // 64 blocks -> 16384 threads
  float4 s; s.x=0.f; s.y=0.f; s.z=0.f; s.w=0.f;
  #pragma unroll 4
  for (int c=0;c<128;++c){
    float4 p = *(const float4*)&part[(size_t)c*(NB*NT) + (size_t)i4*4];
    s.x += p.x; s.y += p.y; s.z += p.z; s.w += p.w;
  }
  *(float4*)&out[(size_t)i4*4] = s;
}

extern "C" void kernel_launch(void* const* d_in, const int* in_sizes, int n_in,
                              void* d_out, int out_size, void* d_ws, size_t ws_size,
                              hipStream_t stream){
  const float* x    = (const float*)d_in[0];
  const float* fb   = (const float*)d_in[1];
  const float* encw = (const float*)d_in[2];
  const float* encb = (const float*)d_in[3];
  const float* upw  = (const float*)d_in[4];
  const float* upb  = (const float*)d_in[5];
  const float* dnw  = (const float*)d_in[6];
  const float* dnb  = (const float*)d_in[7];
  const float* decw = (const float*)d_in[8];
  const float* decb = (const float*)d_in[9];
  float* out = (float*)d_out;
  char* ws = (char*)d_ws;

  size_t o = 0;
  float* bufA = (float*)(ws + o); o += (size_t)NB*NC*NT*4;   // also reused as `part`
  float* bufB = (float*)(ws + o); o += (size_t)NB*NC*NT*4;
  u32*  keys  = (u32*)(ws + o);   o += (size_t)NB*NUP*1024*4;
  u32*  hist1 = (u32*)(ws + o);   o += 1024*NB*4;
  u32*  hist2 = (u32*)(ws + o);   o += 1024*NB*4;
  u32*  cstar = (u32*)(ws + o);   o += 64;
  u32*  nab   = (u32*)(ws + o);   o += 64;
  u32*  t0k   = (u32*)(ws + o);   o += 64;
  int*  cnt   = (int*)(ws + o);   o += 64;
  float* tv   = (float*)(ws + o); o += NB*64*4;
  int*  ti    = (int*)(ws + o);   o += NB*64*4;
  float* cval = (float*)(ws + o); o += (size_t)NB*CAP*4;
  int*  cidx  = (int*)(ws + o);   o += (size_t)NB*CAP*4;
  u16*  wdil  = (u16*)(ws + o);   o += (size_t)12*65536*2;
  u16*  wup   = (u16*)(ws + o);   o += (size_t)4*128*1024*2;
  u16*  wfb   = (u16*)(ws + o);   o += (size_t)128*1024*2;
  float* part = bufA;   // decoder-input buffer dead once k_stack(dec) finishes

  k_prep<<<dim3(352), dim3(256), 0, stream>>>(encw, decw, upw, fb, wdil, wup, wfb, hist1, hist2, cnt);
  k_fb<<<dim3(256,NB), dim3(256), 0, stream>>>(x, wfb, bufA);

  // fused encoder stack: bufA -> bufB  (LDS 256*RS*4 = 135168 B)
  k_stack<<<dim3(256,NB), dim3(1024), 256*RS*4, stream>>>(bufA, bufB, wdil, encb, 0);

  k_sub<<<dim3(32,4,NB), dim3(256), 0, stream>>>(bufB, upw, upb, keys, hist1);
  k_sel<<<dim3(NB), dim3(256), 0, stream>>>(hist1, cstar, nab, t0k, 1);
  k_h2 <<<dim3(4096), dim3(256), 0, stream>>>(keys, cstar, hist2);
  k_sel<<<dim3(NB), dim3(256), 0, stream>>>(hist2, cstar, nab, t0k, 2);
  k_up <<<dim3(256,NB), dim3(256), 2*128*RSH*2, stream>>>(bufB, wup, upb, t0k, cval, cidx, cnt);
  k_top<<<dim3(NB), dim3(256), 0, stream>>>(cval, cidx, cnt, tv, ti);

  // decoder input: bufA = down_b + spikes (fused)
  k_dec0<<<dim3(NB*NC), dim3(256), 0, stream>>>(bufA, dnb, dnw, tv, ti);

  // fused decoder stack: bufA -> bufB
  k_stack<<<dim3(256,NB), dim3(1024), 256*RS*4, stream>>>(bufA, bufB, wdil + (size_t)6*65536, decb, 1);

  k_syn<<<dim3(4,128,NB), dim3(512), 0, stream>>>(bufB, fb, part);
  k_red<<<dim3(64), dim3(256), 0, stream>>>(part, out);
}

// Round 9
// 811.159 us; speedup vs baseline: 1.1174x; 1.1174x over previous
//
#include <hip/hip_runtime.h>
#include <stdint.h>

#define NB  2
#define NC  128
#define NT  32768
#define KFB 512
#define NUP 2048
#define CAP 14336

typedef unsigned int u32;
typedef unsigned short u16;
typedef short s16;
typedef float f32x4 __attribute__((ext_vector_type(4)));
typedef s16 short8 __attribute__((ext_vector_type(8)));
typedef u32 u32x4 __attribute__((ext_vector_type(4)));
typedef u32 u32x2 __attribute__((ext_vector_type(2)));

__device__ __forceinline__ u32 f2key(float v){
  u32 u = __float_as_uint(v);
  return (u & 0x80000000u) ? ~u : (u | 0x80000000u);
}
__device__ __forceinline__ float key2f(u32 k){
  u32 u = (k & 0x80000000u) ? (k & 0x7FFFFFFFu) : ~k;
  return __uint_as_float(u);
}
__device__ __forceinline__ u16 bf16rn(float v){
  u32 u = __float_as_uint(v);
  return (u16)((u + 0x7FFFu + ((u>>16)&1u)) >> 16);
}
__device__ __forceinline__ u32 packhl(float v){
  u16 h = bf16rn(v);
  u16 lo = bf16rn(v - __uint_as_float(((u32)h)<<16));
  return ((u32)h<<16) | lo;
}
__device__ __forceinline__ void unpack8(const u32* p, short8& xh, short8& xl){
  u32x4 r0 = *(const u32x4*)p;
  u32x4 r1 = *(const u32x4*)(p + 4);
  union { u32 u[4]; short8 v; } H, L;
  H.u[0] = __builtin_amdgcn_perm(r0.y, r0.x, 0x07060302u);
  H.u[1] = __builtin_amdgcn_perm(r0.w, r0.z, 0x07060302u);
  H.u[2] = __builtin_amdgcn_perm(r1.y, r1.x, 0x07060302u);
  H.u[3] = __builtin_amdgcn_perm(r1.w, r1.z, 0x07060302u);
  L.u[0] = __builtin_amdgcn_perm(r0.y, r0.x, 0x05040100u);
  L.u[1] = __builtin_amdgcn_perm(r0.w, r0.z, 0x05040100u);
  L.u[2] = __builtin_amdgcn_perm(r1.y, r1.x, 0x05040100u);
  L.u[3] = __builtin_amdgcn_perm(r1.w, r1.z, 0x05040100u);
  xh = H.v; xl = L.v;
}

// LDS row stride (u32) for packed [T][ci] tiles: 132 ≡ 4 (mod 32)
#define RS 132
// LDS row stride (u16) for hi-only / split tiles: 136 u16 = 68 u32 ≡ 4 (mod 32)
#define RSH 136

// ============ K_prep: init + split weights to bf16 hi/lo in MFMA A-fragment order ============
__global__ __launch_bounds__(256) void k_prep(const float* __restrict__ encw,
    const float* __restrict__ decw, const float* __restrict__ upw,
    const float* __restrict__ fbw,
    u16* __restrict__ wdil, u16* __restrict__ wup, u16* __restrict__ wfb,
    u32* __restrict__ h1, u32* __restrict__ h2, int* __restrict__ counts){
  int g = blockIdx.x*256 + threadIdx.x;
  if (g < 2048) h1[g] = 0u;
  else if (g < 4096) h2[g-2048] = 0u;
  if (g < NB) counts[g] = 0;
  if (g < 49152){
    int l = g & 63, mt = (g>>6)&7, s = (g>>9)&7, layer = g>>12;
    const float* W = (layer < 6) ? (encw + (size_t)layer*NC*NC*2)
                                 : (decw + (size_t)(layer-6)*NC*NC*2);
    int co = mt*16 + (l & 15);
    int kb = s*32 + ((l>>4)<<3);
    union { u16 h[8]; u32x4 q; } H, L;
    #pragma unroll
    for (int j=0;j<8;++j){
      int k = kb + j;
      float v = W[((size_t)co*NC + (k&127))*2 + (k>>7)];
      u16 h = bf16rn(v);
      H.h[j] = h;
      L.h[j] = bf16rn(v - __uint_as_float(((u32)h)<<16));
    }
    int unit = g >> 6;
    *(u32x4*)(wdil + (size_t)unit*1024 + (l<<3)) = H.q;
    *(u32x4*)(wdil + (size_t)unit*1024 + 512 + (l<<3)) = L.q;
  } else if (g < 81920){
    int g2 = g - 49152;
    int l = g2 & 63, umt = (g2>>6)&127, s = g2>>13;
    int u = umt*16 + (l & 15);
    int kb = s*32 + ((l>>4)<<3);
    union { u16 h[8]; u32x4 q; } H, L;
    #pragma unroll
    for (int j=0;j<8;++j){
      float v = upw[(size_t)u*NC + kb + j];
      u16 h = bf16rn(v);
      H.h[j] = h;
      L.h[j] = bf16rn(v - __uint_as_float(((u32)h)<<16));
    }
    int unit = g2 >> 6;
    *(u32x4*)(wup + (size_t)unit*1024 + (l<<3)) = H.q;
    *(u32x4*)(wup + (size_t)unit*1024 + 512 + (l<<3)) = L.q;
  } else if (g < 90112){
    int g3 = g - 81920;
    int l = g3 & 63, mt = (g3>>6)&7, s = g3>>9;
    int c = mt*16 + (l & 15);
    int kb = s*32 + ((l>>4)<<3);
    union { u16 h[8]; u32x4 q; } H, L;
    #pragma unroll
    for (int j=0;j<8;++j){
      float v = fbw[(size_t)c*KFB + kb + j];
      u16 h = bf16rn(v);
      H.h[j] = h;
      L.h[j] = bf16rn(v - __uint_as_float(((u32)h)<<16));
    }
    int unit = g3 >> 6;
    *(u32x4*)(wfb + (size_t)unit*1024 + (l<<3)) = H.q;
    *(u32x4*)(wfb + (size_t)unit*1024 + 512 + (l<<3)) = L.q;
  }
}

// ============ K1: filterbank analysis — bf16x3 MFMA ============
__global__ __launch_bounds__(256) void k_fb(const float* __restrict__ x,
    const u16* __restrict__ wfb, float* __restrict__ spec){
  __shared__ u32 xw[640];
  const int tid = threadIdx.x;
  const int t0 = blockIdx.x << 7;
  const int b  = blockIdx.y;
  const int lane = tid & 63, w = tid >> 6;
  const int wy = w >> 1, wx = w & 1;
  const int quad = lane >> 4, l15 = lane & 15;
  for (int i = tid; i < 640; i += 256){
    int t = t0 - 256 + i;
    float v = ((u32)t < (u32)NT) ? x[b*NT + t] : 0.0f;
    xw[i] = packhl(v);
  }
  __syncthreads();
  f32x4 acc[4][4] = {};
  for (int s = 0; s < 16; ++s){
    short8 ah[4], al[4];
    #pragma unroll
    for (int mt=0; mt<4; ++mt){
      const u16* p = wfb + (size_t)(s*8 + wy*4 + mt)*1024 + (lane<<3);
      ah[mt] = *(const short8*)p;
      al[mt] = *(const short8*)(p + 512);
    }
    short8 xh[4], xl[4];
    #pragma unroll
    for (int nt=0; nt<4; ++nt){
      int base = s*32 + quad*8 + (wx<<6) + (nt<<4) + l15;
      u32 r[8];
      #pragma unroll
      for (int j=0;j<8;++j) r[j] = xw[base + j];
      union { u32 u[4]; short8 v; } H, L;
      H.u[0] = __builtin_amdgcn_perm(r[1], r[0], 0x07060302u);
      H.u[1] = __builtin_amdgcn_perm(r[3], r[2], 0x07060302u);
      H.u[2] = __builtin_amdgcn_perm(r[5], r[4], 0x07060302u);
      H.u[3] = __builtin_amdgcn_perm(r[7], r[6], 0x07060302u);
      L.u[0] = __builtin_amdgcn_perm(r[1], r[0], 0x05040100u);
      L.u[1] = __builtin_amdgcn_perm(r[3], r[2], 0x05040100u);
      L.u[2] = __builtin_amdgcn_perm(r[5], r[4], 0x05040100u);
      L.u[3] = __builtin_amdgcn_perm(r[7], r[6], 0x05040100u);
      xh[nt] = H.v; xl[nt] = L.v;
    }
    #pragma unroll
    for (int mt=0; mt<4; ++mt){
      #pragma unroll
      for (int nt=0; nt<4; ++nt){
        acc[mt][nt] = __builtin_amdgcn_mfma_f32_16x16x32_bf16(ah[mt], xh[nt], acc[mt][nt], 0,0,0);
        acc[mt][nt] = __builtin_amdgcn_mfma_f32_16x16x32_bf16(ah[mt], xl[nt], acc[mt][nt], 0,0,0);
        acc[mt][nt] = __builtin_amdgcn_mfma_f32_16x16x32_bf16(al[mt], xh[nt], acc[mt][nt], 0,0,0);
      }
    }
  }
  #pragma unroll
  for (int mt=0; mt<4; ++mt){
    #pragma unroll
    for (int r=0; r<4; ++r){
      const int c = (wy<<6) + (mt<<4) + (quad<<2) + r;
      float* po = spec + (size_t)(b*NC+c)*NT + t0 + (wx<<6) + l15;
      #pragma unroll
      for (int nt=0; nt<4; ++nt) po[nt<<4] = acc[mt][nt][r];
    }
  }
}

// ============ K2a: fused 6-layer ENCODER stack — r6 core (packed u32, x3, no prefetch) ============
__global__ __launch_bounds__(1024,4) void k_stack(const float* __restrict__ xin,
    float* __restrict__ xout, const u16* __restrict__ wf,
    const float* __restrict__ biases, int mode){
  extern __shared__ u32 lx[];           // [row 256][RS]
  const int tid = threadIdx.x;
  const int b  = blockIdx.y;
  const int T0 = blockIdx.x << 7;
  const int row0g = mode ? (T0 - 122) : T0;
  const int lane = tid & 63, w = tid >> 6;
  const int wm = w >> 2, wn = w & 3;
  const int quad = lane >> 4, l15 = lane & 15;
  {
    const float* xb = xin + (size_t)b*NC*NT;
    const int row = tid & 255;
    const int ci0 = (tid >> 8) << 5;
    const int tg = row0g + row;
    const bool ok = ((u32)tg < (u32)NT);
    const float* src = xb + (size_t)ci0*NT + tg;
    u32* dst = lx + row*RS + ci0;
    #pragma unroll
    for (int g=0; g<8; ++g){
      u32x4 q;
      #pragma unroll
      for (int k=0;k<4;++k){
        float v = ok ? src[(size_t)(g*4 + k)*NT] : 0.0f;
        q[k] = packhl(v);
      }
      *(u32x4*)(dst + g*4) = q;
    }
  }
  const int dils[6] = {1,3,9,27,81,1};
  const int Hrem[6] = {121,118,109,82,1,0};
  #pragma unroll 1
  for (int l = 0; l < 6; ++l){
    const int d = dils[l];
    const int o0 = mode ? -d : 0;
    const int o1 = mode ? 0 : d;
    const int lo = mode ? (122 - Hrem[l]) : 0;
    const int hi = mode ? 250 : (128 + Hrem[l]);
    const u16* wl = wf + ((size_t)l << 16);
    __syncthreads();
    bool act[4];
    #pragma unroll
    for (int nt=0;nt<4;++nt){
      const int Tst = (wn<<6) + (nt<<4);
      act[nt] = (Tst + 16 > lo) && (Tst < hi);
    }
    f32x4 acc[2][4] = {};
    #pragma unroll 1
    for (int s = 0; s < 8; ++s){
      short8 cah[2], cal[2];
      #pragma unroll
      for (int mt=0;mt<2;++mt){
        const u16* p = wl + (size_t)(((s<<3) + (wm<<1) + mt) << 10) + (lane<<3);
        cah[mt] = *(const short8*)p;
        cal[mt] = *(const short8*)(p + 512);
      }
      const int o = (s >= 4) ? o1 : o0;
      const int cig = (s & 3) << 5;
      #pragma unroll
      for (int nt=0;nt<4;++nt){
        if (!act[nt]) continue;
        const int T = ((wn<<6) + (nt<<4) + l15 + o) & 255;
        const int idx = T*RS + cig + (quad<<3);
        short8 xh, xl;
        unpack8(&lx[idx], xh, xl);
        acc[0][nt] = __builtin_amdgcn_mfma_f32_16x16x32_bf16(cah[0], xh, acc[0][nt], 0,0,0);
        acc[0][nt] = __builtin_amdgcn_mfma_f32_16x16x32_bf16(cah[0], xl, acc[0][nt], 0,0,0);
        acc[0][nt] = __builtin_amdgcn_mfma_f32_16x16x32_bf16(cal[0], xh, acc[0][nt], 0,0,0);
        acc[1][nt] = __builtin_amdgcn_mfma_f32_16x16x32_bf16(cah[1], xh, acc[1][nt], 0,0,0);
        acc[1][nt] = __builtin_amdgcn_mfma_f32_16x16x32_bf16(cah[1], xl, acc[1][nt], 0,0,0);
        acc[1][nt] = __builtin_amdgcn_mfma_f32_16x16x32_bf16(cal[1], xh, acc[1][nt], 0,0,0);
      }
    }
    __syncthreads();
    const float* bl = biases + l*NC;
    const bool last = (l == 5);
    #pragma unroll
    for (int mt=0;mt<2;++mt){
      const int cobase = (wm<<5) + (mt<<4) + (quad<<2);
      float bv[4];
      #pragma unroll
      for (int r=0;r<4;++r) bv[r] = bl[cobase + r];
      #pragma unroll
      for (int nt=0;nt<4;++nt){
        if (!act[nt]) continue;
        const int T = (wn<<6) + (nt<<4) + l15;
        const int idx = T*RS + cobase;
        u32x4 xo = *(const u32x4*)&lx[idx];
        const int tg = row0g + T;
        const bool tvld = ((u32)tg < (u32)NT);
        float nv[4];
        #pragma unroll
        for (int r=0;r<4;++r){
          float oldv = __uint_as_float(xo[r] & 0xFFFF0000u) + __uint_as_float(xo[r] << 16);
          float h = acc[mt][nt][r] + bv[r];
          h = (h >= 0.f) ? h : 0.2f*h;
          float xn = oldv + h;
          nv[r] = tvld ? xn : 0.0f;
        }
        if (!last){
          u32x4 np;
          #pragma unroll
          for (int r=0;r<4;++r) np[r] = packhl(nv[r]);
          *(u32x4*)&lx[idx] = np;
        } else {
          const bool rowok = mode ? (T >= 122 && T < 250) : (T < 128);
          if (rowok){
            float* po = xout + (size_t)(b*NC + cobase)*NT + tg;
            #pragma unroll
            for (int r=0;r<4;++r) po[(size_t)r*NT] = nv[r];
          }
        }
      }
    }
  }
}

// ============ K2b: fused 6-layer DECODER stack — bf16-hi LDS, x2 MFMA, 2 blocks/CU ============
// x stored hi-only (post-selection path, quantization ok). LDS 256*RSH*2 = 69632 B.
__global__ __launch_bounds__(1024,8) void k_stack2(const float* __restrict__ xin,
    float* __restrict__ xout, const u16* __restrict__ wf,
    const float* __restrict__ biases){
  extern __shared__ u16 lx2[];          // [row 256][RSH]
  const int tid = threadIdx.x;
  const int b  = blockIdx.y;
  const int T0 = blockIdx.x << 7;
  const int row0g = T0 - 122;
  const int lane = tid & 63, w = tid >> 6;
  const int wm = w >> 2, wn = w & 3;
  const int quad = lane >> 4, l15 = lane & 15;
  {
    const float* xb = xin + (size_t)b*NC*NT;
    const int row = tid & 255;
    const int ci0 = (tid >> 8) << 5;
    const int tg = row0g + row;
    const bool ok = ((u32)tg < (u32)NT);
    const float* src = xb + (size_t)ci0*NT + tg;
    u16* dst = lx2 + row*RSH + ci0;
    #pragma unroll
    for (int g=0; g<4; ++g){
      union { u16 h[8]; short8 v; } H;
      #pragma unroll
      for (int j=0;j<8;++j){
        float v = ok ? src[(size_t)(g*8 + j)*NT] : 0.0f;
        H.h[j] = bf16rn(v);
      }
      *(short8*)(dst + (g<<3)) = H.v;
    }
  }
  const int dils[6] = {1,3,9,27,81,1};
  const int Hrem[6] = {121,118,109,82,1,0};
  #pragma unroll 1
  for (int l = 0; l < 6; ++l){
    const int d = dils[l];
    const int o0 = -d, o1 = 0;
    const int lo = 122 - Hrem[l];
    const u16* wl = wf + ((size_t)l << 16);
    __syncthreads();
    bool act[4];
    #pragma unroll
    for (int nt=0;nt<4;++nt){
      const int Tst = (wn<<6) + (nt<<4);
      act[nt] = (Tst + 16 > lo);
    }
    f32x4 acc[2][4] = {};
    #pragma unroll 1
    for (int s = 0; s < 8; ++s){
      short8 cah[2], cal[2];
      #pragma unroll
      for (int mt=0;mt<2;++mt){
        const u16* p = wl + (size_t)(((s<<3) + (wm<<1) + mt) << 10) + (lane<<3);
        cah[mt] = *(const short8*)p;
        cal[mt] = *(const short8*)(p + 512);
      }
      const int o = (s >= 4) ? o1 : o0;
      const int cig = (s & 3) << 5;
      #pragma unroll
      for (int nt=0;nt<4;++nt){
        if (!act[nt]) continue;
        const int T = ((wn<<6) + (nt<<4) + l15 + o) & 255;
        const int base = T*RSH + cig + (quad<<3);
        short8 xh = *(const short8*)&lx2[base];
        acc[0][nt] = __builtin_amdgcn_mfma_f32_16x16x32_bf16(cah[0], xh, acc[0][nt], 0,0,0);
        acc[0][nt] = __builtin_amdgcn_mfma_f32_16x16x32_bf16(cal[0], xh, acc[0][nt], 0,0,0);
        acc[1][nt] = __builtin_amdgcn_mfma_f32_16x16x32_bf16(cah[1], xh, acc[1][nt], 0,0,0);
        acc[1][nt] = __builtin_amdgcn_mfma_f32_16x16x32_bf16(cal[1], xh, acc[1][nt], 0,0,0);
      }
    }
    __syncthreads();
    const float* bl = biases + l*NC;
    const bool last = (l == 5);
    #pragma unroll
    for (int mt=0;mt<2;++mt){
      const int cobase = (wm<<5) + (mt<<4) + (quad<<2);
      float bv[4];
      #pragma unroll
      for (int r=0;r<4;++r) bv[r] = bl[cobase + r];
      #pragma unroll
      for (int nt=0;nt<4;++nt){
        if (!act[nt]) continue;
        const int T = (wn<<6) + (nt<<4) + l15;
        const int base = T*RSH + cobase;
        union { u16 h[4]; u32x2 q; } HH;
        HH.q = *(const u32x2*)&lx2[base];
        const int tg = row0g + T;
        const bool tvld = ((u32)tg < (u32)NT);
        float nv[4];
        #pragma unroll
        for (int r=0;r<4;++r){
          float oldv = __uint_as_float(((u32)HH.h[r])<<16);
          float h = acc[mt][nt][r] + bv[r];
          h = (h >= 0.f) ? h : 0.2f*h;
          float xn = oldv + h;
          nv[r] = tvld ? xn : 0.0f;
        }
        if (!last){
          #pragma unroll
          for (int r=0;r<4;++r) HH.h[r] = bf16rn(nv[r]);
          *(u32x2*)&lx2[base] = HH.q;
        } else {
          if (T >= 122 && T < 250){
            float* po = xout + (size_t)(b*NC + cobase)*NT + tg;
            #pragma unroll
            for (int r=0;r<4;++r) po[(size_t)r*NT] = nv[r];
          }
        }
      }
    }
  }
}

// ============ K3a: up-proj on t-subsample (fp32, keys + coarse hist) ============
__global__ __launch_bounds__(256) void k_sub(const float* __restrict__ enc,
                                             const float* __restrict__ upw,
                                             const float* __restrict__ upb,
                                             u32* __restrict__ keys,
                                             u32* __restrict__ hist1){
  const int u0 = blockIdx.x * 64;
  const int i0 = blockIdx.y * 256;
  const int b  = blockIdx.z;
  __shared__ float uwl[32][68];
  __shared__ float ec[32][260];
  __shared__ u32 lh[1024];
  const int tid = threadIdx.x;
  for (int i=tid;i<1024;i+=256) lh[i] = 0u;
  const int ug = tid & 15;
  const int ig = tid >> 4;
  float acc[4][16];
  #pragma unroll
  for (int i=0;i<4;++i){
    #pragma unroll
    for (int j=0;j<16;++j) acc[i][j]=0.0f;
  }
  for (int c0=0;c0<NC;c0+=32){
    __syncthreads();
    #pragma unroll
    for (int i=0;i<8;++i){
      int flat = i*256+tid;
      uwl[flat & 31][flat >> 5] = upw[(size_t)(u0 + (flat>>5))*NC + c0 + (flat&31)];
    }
    #pragma unroll
    for (int i=0;i<32;++i){
      int flat = i*256+tid;
      ec[flat >> 8][flat & 255] = enc[(size_t)(b*NC + c0 + (flat>>8))*NT + (size_t)(i0 + (flat&255))*32];
    }
    __syncthreads();
    #pragma unroll 2
    for (int cc=0;cc<32;++cc){
      float a[4], bb[16];
      *(float4*)&a[0] = *(const float4*)&uwl[cc][ug*4];
      #pragma unroll
      for (int m=0;m<4;++m)
        *(float4*)&bb[m*4] = *(const float4*)&ec[cc][ig*16 + m*4];
      #pragma unroll
      for (int i=0;i<4;++i){
        #pragma unroll
        for (int j=0;j<16;++j)
          acc[i][j] = fmaf(a[i], bb[j], acc[i][j]);
      }
    }
  }
  #pragma unroll
  for (int i=0;i<4;++i){
    int u = u0 + ug*4 + i;
    float ub = upb[u];
    #pragma unroll
    for (int j=0;j<16;++j){
      float v = acc[i][j] + ub;
      u32 k = f2key(v);
      keys[(size_t)(b*NUP + u)*1024 + i0 + ig*16 + j] = k;
      atomicAdd(&lh[k >> 22], 1u);
    }
  }
  __syncthreads();
  for (int i=tid;i<1024;i+=256){
    u32 c = lh[i];
    if (c) atomicAdd(&hist1[b*1024 + i], c);
  }
}

// ============ K3sel: suffix-scan histogram, pick rank-64 bin ============
__global__ __launch_bounds__(256) void k_sel(const u32* __restrict__ hist,
                                             u32* __restrict__ cstar,
                                             u32* __restrict__ nab,
                                             u32* __restrict__ t0key,
                                             int phase){
  const int b = blockIdx.x;
  __shared__ u32 s1[1024];
  __shared__ u32 s2[1024];
  __shared__ int red[256];
  const int tid = threadIdx.x;
  for (int i=tid;i<1024;i+=256) s1[i] = hist[b*1024 + i];
  __syncthreads();
  u32* cur = s1; u32* nxt = s2;
  for (int off=1; off<1024; off<<=1){
    for (int i=tid;i<1024;i+=256){
      u32 v = cur[i];
      if (i + off < 1024) v += cur[i+off];
      nxt[i] = v;
    }
    __syncthreads();
    u32* t = cur; cur = nxt; nxt = t;
  }
  u32 off0 = (phase==1) ? 0u : nab[b];
  int best = -1;
  for (int i=tid;i<1024;i+=256)
    if (off0 + cur[i] >= 64u && i > best) best = i;
  red[tid] = best;
  __syncthreads();
  for (int st=128; st>0; st>>=1){
    if (tid < st) red[tid] = max(red[tid], red[tid+st]);
    __syncthreads();
  }
  if (tid == 0){
    int bi = (red[0] < 0) ? 0 : red[0];
    if (phase == 1){
      cstar[b] = (u32)bi;
      nab[b] = (bi < 1023) ? cur[bi+1] : 0u;
    } else {
      t0key[b] = (cstar[b] << 22) | (((u32)bi) << 12);
    }
  }
}

// ============ K3h2: fine histogram within coarse bin ============
__global__ void k_h2(const u32* __restrict__ keys, const u32* __restrict__ cstar,
                     u32* __restrict__ hist2){
  const u32 c0 = cstar[0], c1 = cstar[1];
  int i = blockIdx.x*256 + threadIdx.x;
  const int total = NB*NUP*1024;
  const int stride = gridDim.x*256;
  for (; i < total; i += stride){
    u32 k = keys[i];
    u32 cs = (i >> 21) ? c1 : c0;
    if ((k >> 22) == cs) atomicAdd(&hist2[((u32)(i>>21)<<10) + ((k>>12) & 1023u)], 1u);
  }
}

// ============ K3b: full up-proj — split hi/lo LDS, flattened (uc,s) loop w/ prefetch ============
__global__ __launch_bounds__(256,2) void k_up(const float* __restrict__ enc,
    const u16* __restrict__ wf, const float* __restrict__ upb,
    const u32* __restrict__ t0key, float* __restrict__ cval,
    int* __restrict__ cidx, int* __restrict__ counts){
  extern __shared__ u16 ls[];
  u16* lhh = ls;
  u16* lll = ls + 128*RSH;
  const int tid = threadIdx.x;
  const int t0 = blockIdx.x << 7;
  const int b  = blockIdx.y;
  const int lane = tid & 63, w = tid >> 6;
  const int wy = w >> 1, wx = w & 1;
  const int quad = lane >> 4, l15 = lane & 15;
  {
    const float* xb = enc + (size_t)b*NC*NT + t0;
    const int row = tid >> 1;
    const int ci0 = (tid & 1) << 6;
    const float* src = xb + (size_t)ci0*NT + row;
    u16* dh = lhh + row*RSH + ci0;
    u16* dl = lll + row*RSH + ci0;
    #pragma unroll
    for (int g=0; g<8; ++g){
      union { u16 h[8]; short8 v; } H, L;
      #pragma unroll
      for (int j=0;j<8;++j){
        float v = src[(size_t)(g*8 + j)*NT];
        u16 hh = bf16rn(v);
        H.h[j] = hh;
        L.h[j] = bf16rn(v - __uint_as_float(((u32)hh)<<16));
      }
      *(short8*)(dh + (g<<3)) = H.v;
      *(short8*)(dl + (g<<3)) = L.v;
    }
  }
  __syncthreads();
  float T0 = key2f(t0key[b]);
  T0 -= fabsf(T0)*3e-4f + 1e-5f;
  short8 cah[4], cal[4], nah[4], nal[4];
  {
    #pragma unroll
    for (int mt=0;mt<4;++mt){
      const u16* p = wf + (size_t)((wy*4 + mt) << 10) + (lane<<3);
      cah[mt] = *(const short8*)p; cal[mt] = *(const short8*)(p + 512);
    }
  }
  f32x4 acc[4][4] = {};
  #pragma unroll 1
  for (int ss = 0; ss < 64; ++ss){
    const int uc = ss >> 2, s = ss & 3;
    const int ssn = (ss < 63) ? (ss + 1) : 63;
    const int ucn = ssn >> 2, sn = ssn & 3;
    #pragma unroll
    for (int mt=0;mt<4;++mt){
      const u16* p = wf + (size_t)((sn*128 + ucn*8 + wy*4 + mt) << 10) + (lane<<3);
      nah[mt] = *(const short8*)p; nal[mt] = *(const short8*)(p + 512);
    }
    const int cig = s << 5;
    #pragma unroll
    for (int nt=0;nt<4;++nt){
      const int T = (wx<<6) + (nt<<4) + l15;
      const int base = T*RSH + cig + (quad<<3);
      short8 xh = *(const short8*)&lhh[base];
      short8 xl = *(const short8*)&lll[base];
      #pragma unroll
      for (int mt=0;mt<4;++mt){
        acc[mt][nt] = __builtin_amdgcn_mfma_f32_16x16x32_bf16(cah[mt], xh, acc[mt][nt], 0,0,0);
        acc[mt][nt] = __builtin_amdgcn_mfma_f32_16x16x32_bf16(cah[mt], xl, acc[mt][nt], 0,0,0);
        acc[mt][nt] = __builtin_amdgcn_mfma_f32_16x16x32_bf16(cal[mt], xh, acc[mt][nt], 0,0,0);
      }
    }
    if (s == 3){
      #pragma unroll
      for (int mt=0; mt<4; ++mt){
        #pragma unroll
        for (int r=0; r<4; ++r){
          int u = uc*128 + (wy<<6) + (mt<<4) + (quad<<2) + r;
          float ub = upb[u];
          #pragma unroll
          for (int nt=0; nt<4; ++nt){
            float v = acc[mt][nt][r] + ub;
            if (v >= T0){
              int slot = atomicAdd(&counts[b], 1);
              if (slot < CAP){
                cval[b*CAP + slot] = v;
                cidx[b*CAP + slot] = u*NT + (t0 + (wx<<6) + (nt<<4) + l15);
              }
            }
          }
        }
      }
      #pragma unroll
      for (int mt=0;mt<4;++mt)
        #pragma unroll
        for (int nt=0;nt<4;++nt) acc[mt][nt] = (f32x4){0.f,0.f,0.f,0.f};
    }
    #pragma unroll
    for (int mt=0;mt<4;++mt){ cah[mt] = nah[mt]; cal[mt] = nal[mt]; }
  }
}

// ============ K3c: exact top-64 — register-cached path for n<=8192 ============
__global__ __launch_bounds__(256) void k_top(const float* __restrict__ cval,
                                             const int* __restrict__ cidx,
                                             const int* __restrict__ counts,
                                             float* __restrict__ tv,
                                             int* __restrict__ ti){
  const int b = blockIdx.x;
  __shared__ float lv[CAP];
  __shared__ float sv[256];
  __shared__ int   si[256];
  const int tid = threadIdx.x;
  int n = counts[b]; if (n > CAP) n = CAP;
  if (n <= 8192){
    float v[32];
    #pragma unroll
    for (int r=0;r<32;++r){
      int i = r*256 + tid;
      v[r] = (i < n) ? cval[b*CAP+i] : -3.4e38f;
    }
    const int lane = tid & 63, wv = tid >> 6;
    for (int r=0;r<64;++r){
      float best = v[0]; int bidx = 0;
      #pragma unroll
      for (int k=1;k<32;++k){ if (v[k] > best){ best = v[k]; bidx = k; } }
      int gi = bidx*256 + tid;
      #pragma unroll
      for (int off=32; off>0; off>>=1){
        float ov = __shfl_down(best, off);
        int oi = __shfl_down(gi, off);
        if (ov > best){ best = ov; gi = oi; }
      }
      if (lane == 0){ sv[wv] = best; si[wv] = gi; }
      __syncthreads();
      if (tid == 0){
        float bb = sv[0]; int bbi = si[0];
        #pragma unroll
        for (int k=1;k<4;++k) if (sv[k] > bb){ bb = sv[k]; bbi = si[k]; }
        si[4] = bbi;
        if (bb > -3.0e38f){ tv[b*64+r] = bb; ti[b*64+r] = cidx[b*CAP + bbi]; }
        else { tv[b*64+r] = 0.0f; ti[b*64+r] = 0; }
      }
      __syncthreads();
      int wini = si[4];
      if ((wini & 255) == tid) v[wini >> 8] = -3.4e38f;
    }
  } else {
    for (int i=tid;i<n;i+=256) lv[i] = cval[b*CAP+i];
    __syncthreads();
    for (int r=0;r<64;++r){
      float best = -3.4e38f; int bi = -1;
      for (int i=tid;i<n;i+=256){
        float v = lv[i];
        if (v > best){ best = v; bi = i; }
      }
      sv[tid]=best; si[tid]=bi;
      __syncthreads();
      for (int st=128; st>0; st>>=1){
        if (tid < st && sv[tid+st] > sv[tid]){ sv[tid]=sv[tid+st]; si[tid]=si[tid+st]; }
        __syncthreads();
      }
      if (tid == 0){
        int kb = si[0];
        if (kb >= 0){
          tv[b*64+r] = sv[0];
          ti[b*64+r] = cidx[b*CAP+kb];
          lv[kb] = -3.4e38f;
        } else { tv[b*64+r] = 0.0f; ti[b*64+r] = 0; }
      }
      __syncthreads();
    }
  }
}

// ============ K4: fused decoder-input init: bias fill + spike scatter ============
__global__ void k_dec0(float* __restrict__ dst, const float* __restrict__ dnb,
                       const float* __restrict__ dnw,
                       const float* __restrict__ tv, const int* __restrict__ ti){
  const int b = blockIdx.x >> 7, c = blockIdx.x & 127;
  float v = dnb[c];
  float4 vv; vv.x=v; vv.y=v; vv.z=v; vv.w=v;
  float* row = dst + (size_t)(b*NC+c)*NT;
  for (int i=threadIdx.x; i < NT/4; i += 256) *(float4*)&row[i*4] = vv;
  __syncthreads();
  if (threadIdx.x < 64){
    int r = threadIdx.x;
    float sv = tv[b*64+r];
    int idx = ti[b*64+r];
    int u = idx / NT, t = idx - u*NT;
    atomicAdd(&row[t], dnw[(size_t)c*NUP + u] * sv);
  }
}

// ============ K6: transposed filterbank synthesis — 1 channel/block (r7 best) ============
#define TS 4096
__global__ __launch_bounds__(256) void k_syn(const float* __restrict__ dec,
                                             const float* __restrict__ fb,
                                             float* __restrict__ part){
  const int ts = blockIdx.x;    // 8
  const int c  = blockIdx.y;    // 128
  const int b  = blockIdx.z;
  const int t0 = ts * TS;
  __shared__ float win2[16*289 + 8];
  __shared__ float fbl[512];
  const int tid = threadIdx.x;
  const int tl = tid * 16;
  float acc[16];
  #pragma unroll
  for (int j=0;j<16;++j) acc[j] = 0.0f;
  for (int i=tid; i < TS+511; i += 256){
    int t = t0 - 255 + i;
    win2[(i & 15)*289 + (i >> 4)] = ((u32)t < (u32)NT) ? dec[(size_t)(b*NC+c)*NT + t] : 0.0f;
  }
  for (int i=tid; i<512; i+=256) fbl[i] = fb[c*KFB + i];
  __syncthreads();
  float w[23];
  #pragma unroll
  for (int k=0;k<23;++k){
    int i = tl + 504 + k;
    w[k] = win2[(i & 15)*289 + (i >> 4)];
  }
  for (int G=0; G<64; ++G){
    float4 f0 = *(const float4*)&fbl[G*8];
    float4 f1 = *(const float4*)&fbl[G*8+4];
    float fq[8] = {f0.x, f0.y, f0.z, f0.w, f1.x, f1.y, f1.z, f1.w};
    #pragma unroll
    for (int q=0;q<8;++q){
      #pragma unroll
      for (int jj=0;jj<16;++jj)
        acc[jj] = fmaf(fq[q], w[7-q+jj], acc[jj]);
    }
    if (G != 63){
      #pragma unroll
      for (int k=22;k>=8;--k) w[k] = w[k-8];
      #pragma unroll
      for (int k=0;k<8;++k){
        int i = tl + 496 - 8*G + k;
        w[k] = win2[(i & 15)*289 + (i >> 4)];
      }
    }
  }
  float* po = &part[(size_t)(c*NB + b)*NT + t0 + tl];
  #pragma unroll
  for (int m=0;m<4;++m){
    float4 ov; ov.x=acc[m*4+0]; ov.y=acc[m*4+1]; ov.z=acc[m*4+2]; ov.w=acc[m*4+3];
    *(float4*)&po[m*4] = ov;
  }
}

// ============ K6r: reduce 128 partial slices -> out (float4) ============
__global__ void k_red(const float* __restrict__ part, float* __restrict__ out){
  int i4 = blockIdx.x*256 + threadIdx.x;   // 64 blocks -> 16384 threads
  float4 s; s.x=0.f; s.y=0.f; s.z=0.f; s.w=0.f;
  #pragma unroll 4
  for (int c=0;c<128;++c){
    float4 p = *(const float4*)&part[(size_t)c*(NB*NT) + (size_t)i4*4];
    s.x += p.x; s.y += p.y; s.z += p.z; s.w += p.w;
  }
  *(float4*)&out[(size_t)i4*4] = s;
}

extern "C" void kernel_launch(void* const* d_in, const int* in_sizes, int n_in,
                              void* d_out, int out_size, void* d_ws, size_t ws_size,
                              hipStream_t stream){
  const float* x    = (const float*)d_in[0];
  const float* fb   = (const float*)d_in[1];
  const float* encw = (const float*)d_in[2];
  const float* encb = (const float*)d_in[3];
  const float* upw  = (const float*)d_in[4];
  const float* upb  = (const float*)d_in[5];
  const float* dnw  = (const float*)d_in[6];
  const float* dnb  = (const float*)d_in[7];
  const float* decw = (const float*)d_in[8];
  const float* decb = (const float*)d_in[9];
  float* out = (float*)d_out;
  char* ws = (char*)d_ws;

  size_t o = 0;
  float* bufA = (float*)(ws + o); o += (size_t)NB*NC*NT*4;   // also reused as `part`
  float* bufB = (float*)(ws + o); o += (size_t)NB*NC*NT*4;
  u32*  keys  = (u32*)(ws + o);   o += (size_t)NB*NUP*1024*4;
  u32*  hist1 = (u32*)(ws + o);   o += 1024*NB*4;
  u32*  hist2 = (u32*)(ws + o);   o += 1024*NB*4;
  u32*  cstar = (u32*)(ws + o);   o += 64;
  u32*  nab   = (u32*)(ws + o);   o += 64;
  u32*  t0k   = (u32*)(ws + o);   o += 64;
  int*  cnt   = (int*)(ws + o);   o += 64;
  float* tv   = (float*)(ws + o); o += NB*64*4;
  int*  ti    = (int*)(ws + o);   o += NB*64*4;
  float* cval = (float*)(ws + o); o += (size_t)NB*CAP*4;
  int*  cidx  = (int*)(ws + o);   o += (size_t)NB*CAP*4;
  u16*  wdil  = (u16*)(ws + o);   o += (size_t)12*65536*2;
  u16*  wup   = (u16*)(ws + o);   o += (size_t)4*128*1024*2;
  u16*  wfb   = (u16*)(ws + o);   o += (size_t)128*1024*2;
  float* part = bufA;   // decoder-input buffer dead once k_stack2 finishes

  k_prep<<<dim3(352), dim3(256), 0, stream>>>(encw, decw, upw, fb, wdil, wup, wfb, hist1, hist2, cnt);
  k_fb<<<dim3(256,NB), dim3(256), 0, stream>>>(x, wfb, bufA);

  // fused encoder stack (x3, packed u32): bufA -> bufB
  k_stack<<<dim3(256,NB), dim3(1024), 256*RS*4, stream>>>(bufA, bufB, wdil, encb, 0);

  k_sub<<<dim3(32,4,NB), dim3(256), 0, stream>>>(bufB, upw, upb, keys, hist1);
  k_sel<<<dim3(NB), dim3(256), 0, stream>>>(hist1, cstar, nab, t0k, 1);
  k_h2 <<<dim3(4096), dim3(256), 0, stream>>>(keys, cstar, hist2);
  k_sel<<<dim3(NB), dim3(256), 0, stream>>>(hist2, cstar, nab, t0k, 2);
  k_up <<<dim3(256,NB), dim3(256), 2*128*RSH*2, stream>>>(bufB, wup, upb, t0k, cval, cidx, cnt);
  k_top<<<dim3(NB), dim3(256), 0, stream>>>(cval, cidx, cnt, tv, ti);

  // decoder input: bufA = down_b + spikes (fused)
  k_dec0<<<dim3(NB*NC), dim3(256), 0, stream>>>(bufA, dnb, dnw, tv, ti);

  // fused decoder stack (x2, bf16-hi LDS, 2 blocks/CU): bufA -> bufB
  k_stack2<<<dim3(256,NB), dim3(1024), 256*RSH*2, stream>>>(bufA, bufB, wdil + (size_t)6*65536, decb);

  k_syn<<<dim3(8,128,NB), dim3(256), 0, stream>>>(bufB, fb, part);
  k_red<<<dim3(64), dim3(256), 0, stream>>>(part, out);
}